// Round 12
// baseline (39.810 us; speedup 1.0000x reference)
//
#include <hip/hip_runtime.h>
#include <math.h>

// Problem constants (fixed by setup_inputs)
constexpr int N    = 4;
constexpr int C    = 16;
constexpr int Hin  = 288;
constexpr int Win  = 1216;
constexpr int Hout = 800;
constexpr int Wout = 400;
constexpr int PIX_PER_N = Hout * Wout;       // 320000
constexpr int CH_STRIDE = Hin * Win;         // 350208

// Native clang vector type (HIP float2 is a class type that
// __builtin_nontemporal_store rejects).
typedef float v2f __attribute__((ext_vector_type(2)));

// Base-grid constants (exact reference f32 values; see round-6 derivation).
constexpr double grd = 0.05 * (800.0 / (double)Hout);        // 0.05 (f64)
constexpr float  GR  = (float)grd;                            // f32(0.05)
constexpr float  CX0 = (float)(-10.0 + grd / 2.0);            // f32(-9.975)
constexpr float  CY0 = (float)( 46.0 - grd / 2.0);            // f32(45.975)

// Register barrier: keeps ops separately rounded exactly where the numpy
// reference's ufuncs are separately rounded (correctness-critical near the
// g2~0 projective singularity). Coordinate chain ONLY.
__device__ __forceinline__ float fbar(float x) {
    asm volatile("" : "+v"(x));
    return x;
}

struct Samp {
    int   lb0, lb1;           // clamped dwordx2 load bases (row y0 / y1)
    bool  hi0, hi1, xpair;    // corner-select flags
    float w00, w01, w10, w11; // bilinear weights
};

// Bit-exact coordinate chain (verified round 6: flavor-F einsum, IEEE divs,
// separately-rounded ufunc chain). DO NOT TOUCH.
__device__ __forceinline__ Samp px_chain(int w, int h, const float* th, float shn) {
    float bx = CX0 + fbar(GR * (float)w);
    float by = CY0 - fbar(GR * (float)h);

    float t00 = th[0], t01 = th[1], t02 = th[2];
    float t10 = th[3], t11 = th[4], t12 = th[5];
    float t20 = th[6], t21 = th[7], t22 = th[8];

    float g0 = fbar(__builtin_fmaf(by, t01, fbar(bx * t00))) + t02;
    float g1 = fbar(__builtin_fmaf(by, t11, fbar(bx * t10))) + t12;
    float g2 = fbar(__builtin_fmaf(by, t21, fbar(bx * t20))) + t22;

    float p0 = g0 / g2;
    float p1 = g1 / g2;

    float gx = fbar(p0 / 608.0f) - 1.0f;
    float gy = fbar((p1 - shn) / 144.0f) - 1.0f;

    float ix = (fbar((gx + 1.0f) * (float)Win) - 1.0f) * 0.5f;
    float iy = (fbar((gy + 1.0f) * (float)Hin) - 1.0f) * 0.5f;

    float ix0f = floorf(ix);
    float iy0f = floorf(iy);
    float wx = ix - ix0f;
    float wy = iy - iy0f;

    int x0 = (int)fminf(fmaxf(ix0f,        0.0f), (float)(Win - 1));
    int x1 = (int)fminf(fmaxf(ix0f + 1.0f, 0.0f), (float)(Win - 1));
    int y0 = (int)fminf(fmaxf(iy0f,        0.0f), (float)(Hin - 1));
    int y1 = (int)fminf(fmaxf(iy0f + 1.0f, 0.0f), (float)(Hin - 1));

    float omwx = 1.0f - wx;
    float omwy = 1.0f - wy;

    Samp s;
    s.w00 = omwx * omwy;
    s.w01 = wx * omwy;
    s.w10 = omwx * wy;
    s.w11 = wx * wy;

    int lo0 = y0 * Win + x0;
    int lo1 = y1 * Win + x0;
    s.lb0 = min(lo0, CH_STRIDE - 2);
    s.lb1 = min(lo1, CH_STRIDE - 2);
    s.hi0 = lo0 > s.lb0;
    s.hi1 = lo1 > s.lb1;
    s.xpair = x1 > x0;
    return s;
}

__device__ __forceinline__ float combine(v2f r0, v2f r1, const Samp& s) {
    float v00 = s.hi0   ? r0.y : r0.x;
    float v01 = s.xpair ? r0.y : v00;
    float v10 = s.hi1   ? r1.y : r1.x;
    float v11 = s.xpair ? r1.y : v10;
    return v00 * s.w00 + v01 * s.w01 + v10 * s.w10 + v11 * s.w11;
}

__global__ __launch_bounds__(256) void bev_sample_kernel(
    const float* __restrict__ x,      // (N, C, Hin, Win)
    const float* __restrict__ theta,  // (N, 3, 3)
    const float* __restrict__ shift,  // (N,)
    float* __restrict__ out)          // (N, C, Hout, Wout)
{
    // One thread = 2 horizontally-adjacent pixels (w, w+1), w even.
    // Halves the store instruction stream (8B NT stores) at zero
    // divergence cost; loads remain the proven per-pixel dwordx2 path.
    int tid2 = blockIdx.x * 256 + threadIdx.x;
    if (tid2 >= (N * Hout * Wout) / 2) return;
    int pid = tid2 * 2;

    int w = pid % Wout;               // even; w+1 < Wout (Wout=400 even)
    int t = pid / Wout;
    int h = t % Hout;
    int n = t / Hout;

    const float* th  = theta + n * 9;
    const float  shn = shift[n];

    Samp sa = px_chain(w,     h, th, shn);
    Samp sb = px_chain(w + 1, h, th, shn);

    const float* xb = x + (size_t)n * C * CH_STRIDE;
    float* ob = out + ((size_t)(n * C) * Hout + h) * (size_t)Wout + w; // 8B-aligned

    // Two channel batches of 8: 32 dwordx2 loads in flight per batch.
    #pragma unroll 1
    for (int half = 0; half < 2; ++half) {
        v2f r0a[8], r1a[8], r0b[8], r1b[8];
        #pragma unroll
        for (int j = 0; j < 8; ++j) {
            const float* pch = xb + (size_t)(half * 8 + j) * CH_STRIDE;
            r0a[j] = *reinterpret_cast<const v2f*>(pch + sa.lb0);
            r1a[j] = *reinterpret_cast<const v2f*>(pch + sa.lb1);
            r0b[j] = *reinterpret_cast<const v2f*>(pch + sb.lb0);
            r1b[j] = *reinterpret_cast<const v2f*>(pch + sb.lb1);
        }
        #pragma unroll
        for (int j = 0; j < 8; ++j) {
            v2f rr;
            rr.x = combine(r0a[j], r1a[j], sa);
            rr.y = combine(r0b[j], r1b[j], sb);
            __builtin_nontemporal_store(rr, reinterpret_cast<v2f*>(
                ob + (size_t)(half * 8 + j) * PIX_PER_N));
        }
    }
}

extern "C" void kernel_launch(void* const* d_in, const int* in_sizes, int n_in,
                              void* d_out, int out_size, void* d_ws, size_t ws_size,
                              hipStream_t stream) {
    const float* x     = (const float*)d_in[0];
    const float* theta = (const float*)d_in[1];
    const float* shift = (const float*)d_in[2];
    float* out = (float*)d_out;

    int total2 = (N * Hout * Wout) / 2;              // 640,000 threads
    int blocks = (total2 + 255) / 256;               // 2500
    bev_sample_kernel<<<blocks, 256, 0, stream>>>(x, theta, shift, out);
}